// Round 5
// baseline (512.173 us; speedup 1.0000x reference)
//
#include <hip/hip_runtime.h>
#include <hip/hip_bf16.h>

// ---------------------------------------------------------------------------
// TernaryDense: C[M,N] = A[M,K] (fp32) @ ternary(W[K,N]) (fp32)
// Round 5: 8-phase 256^2 GEMM with LDS->reg reads software-pipelined ONE
// PHASE AHEAD (reads for phase p+1 issued in phase p; compiler emits counted
// lgkmcnt so MFMA never waits on same-phase reads). vmcnt(2) at ph3/ph7.
// T1 XCD swizzle, T2 src-side XOR swizzle (0 conflicts), T5 setprio.
// ---------------------------------------------------------------------------

#define LDSP(p) ((__attribute__((address_space(3))) void*)(p))
#define GLBP(p) ((const __attribute__((address_space(1))) void*)(p))

typedef __attribute__((ext_vector_type(8))) short bf16x8;
typedef __attribute__((ext_vector_type(4))) float f32x4;

static __device__ __forceinline__ unsigned short f2bf_rne(float f) {
    unsigned u = __float_as_uint(f);
    unsigned r = (u + 0x7FFFu + ((u >> 16) & 1u)) >> 16;
    return (unsigned short)r;
}

static __device__ __forceinline__ unsigned short tern_bf16(float v) {
    float a = fabsf(v);
    if (a >= 0.5f && a < 1.5f)
        return (v > 0.0f) ? (unsigned short)0x3F80u : (unsigned short)0xBF80u;
    return (unsigned short)0;
}

// --- pre-pass 1: A fp32 -> bf16 ---------------------------------------------
__global__ __launch_bounds__(256) void cvtA_kernel(
    const float* __restrict__ in, unsigned short* __restrict__ out, long n8) {
    long i = (long)blockIdx.x * blockDim.x + threadIdx.x;
    long stride = (long)gridDim.x * blockDim.x;
    for (; i < n8; i += stride) {
        float4 v0 = *(const float4*)(in + i * 8);
        float4 v1 = *(const float4*)(in + i * 8 + 4);
        unsigned short o[8] = {f2bf_rne(v0.x), f2bf_rne(v0.y), f2bf_rne(v0.z), f2bf_rne(v0.w),
                               f2bf_rne(v1.x), f2bf_rne(v1.y), f2bf_rne(v1.z), f2bf_rne(v1.w)};
        *(int4*)(out + i * 8) = *(const int4*)o;
    }
}

// --- pre-pass 2: ternarize W[K,N] and transpose -> Wt[N,K] bf16 -------------
__global__ __launch_bounds__(256) void ternT_kernel(
    const float* __restrict__ W, unsigned short* __restrict__ Wt, int K, int N) {
    __shared__ unsigned short tile[64][72];
    const int k0 = blockIdx.y * 64;
    const int n0 = blockIdx.x * 64;
    const int t = threadIdx.x;
#pragma unroll
    for (int i = 0; i < 4; ++i) {
        int e = i * 1024 + t * 4;
        int r = e >> 6, c = e & 63;
        float4 v = *(const float4*)(W + (size_t)(k0 + r) * N + n0 + c);
        tile[r][c + 0] = tern_bf16(v.x);
        tile[r][c + 1] = tern_bf16(v.y);
        tile[r][c + 2] = tern_bf16(v.z);
        tile[r][c + 3] = tern_bf16(v.w);
    }
    __syncthreads();
#pragma unroll
    for (int i = 0; i < 2; ++i) {
        int e = i * 2048 + t * 8;
        int n = e >> 6, kk = e & 63;
        unsigned short o[8];
#pragma unroll
        for (int j = 0; j < 8; ++j) o[j] = tile[kk + j][n];
        *(int4*)(Wt + (size_t)(n0 + n) * K + k0 + kk) = *(const int4*)o;
    }
}

// --- pipelined 8-phase 256^2 GEMM, 16x16x32 MFMA ----------------------------
#define BM 256
#define BN 256
#define BK 64

#define FENCE() asm volatile("" ::: "memory")
#define BAR()                          \
    do {                               \
        FENCE();                       \
        __builtin_amdgcn_s_barrier();  \
        FENCE();                       \
    } while (0)

template <int N, int K>
__global__ __launch_bounds__(512, 2) void gemm8pp_kernel(
    const unsigned short* __restrict__ A,   // M x K bf16
    const unsigned short* __restrict__ Bt,  // N x K bf16
    float* __restrict__ C, int M) {
    __shared__ alignas(16) unsigned short lds[2][2][BM * BK];  // 128 KB

    const int t = threadIdx.x;
    const int lane = t & 63;
    const int wave = t >> 6;
    const int wm = wave >> 2;   // 0..1  -> 128 rows
    const int wn = wave & 3;    // 0..3  -> 64 cols
    const int l15 = lane & 15;
    const int kgrp = lane >> 4; // 0..3

    // T1: bijective XCD swizzle (nwg % 8 == 0)
    const int nbx = N / BN;
    const int nwg = nbx * (M / BM);
    const int qq = nwg >> 3;
    const int swz = ((int)blockIdx.x & 7) * qq + ((int)blockIdx.x >> 3);
    const int brow = (swz / nbx) * BM;
    const int bcol = (swz % nbx) * BN;

    constexpr int NKT = K / BK;   // 64
    constexpr int NIT = NKT / 2;  // 32

    // stage one 16KB half (mat 0=A,1=B; h 0/1) of K-tile kt into buffer b.
    // LDS dest linear; inverse T2 swizzle applied to the GLOBAL source addr.
    auto stage_half = [&](int b, int mat, int h, int kt) {
        const unsigned short* sb = mat ? Bt : A;
        const int rowbase = mat ? bcol : brow;
#pragma unroll
        for (int iss = 0; iss < 2; ++iss) {
            int Lb = h * 16384 + iss * 8192 + t * 16;  // byte in 32KB tile
            int row = Lb >> 7;                          // tile row 0..255
            int kb = (Lb & 127) ^ ((row & 7) << 4);     // swizzled k-byte
            const char* src = (const char*)sb +
                ((size_t)(rowbase + row) * K + (size_t)kt * BK) * 2 + kb;
            unsigned short* dst =
                &lds[b][mat][0] + (h * 16384 + iss * 8192 + wave * 1024) / 2;
            __builtin_amdgcn_global_load_lds(GLBP(src), LDSP(dst), 16, 0, 0);
        }
    };

    auto read_A = [&](int b, int mf, int ks) -> bf16x8 {
        int row = wm * 128 + mf * 16 + l15;
        int kb = (kgrp * 16 + ks * 64) ^ ((row & 7) << 4);
        return *(const bf16x8*)((const char*)&lds[b][0][0] + row * 128 + kb);
    };
    auto read_B = [&](int b, int nf, int ks) -> bf16x8 {
        int row = wn * 64 + nf * 16 + l15;
        int kb = (kgrp * 16 + ks * 64) ^ ((row & 7) << 4);
        return *(const bf16x8*)((const char*)&lds[b][1][0] + row * 128 + kb);
    };

    f32x4 acc[8][4] = {};
    // Pipelined register sets. Live ranges interleave so the allocator can
    // overlay afA/afB (and bfr01/bfr23) with the non-pipelined equivalents.
    bf16x8 afA[4][2], afB[4][2], bfr01[2][2], bfr23[2][2];

    // 16 MFMA = one C-quadrant (4 mf x 2 nf x 2 ks)
#define QMFMA(AF, BF, MB, NB)                                                  \
    do {                                                                       \
        __builtin_amdgcn_s_setprio(1);                                         \
        _Pragma("unroll") for (int ks = 0; ks < 2; ++ks)                       \
            _Pragma("unroll") for (int mf = 0; mf < 4; ++mf)                   \
                _Pragma("unroll") for (int nf = 0; nf < 2; ++nf)               \
                    acc[(MB) + mf][(NB) + nf] =                                \
                        __builtin_amdgcn_mfma_f32_16x16x32_bf16(               \
                            AF[mf][ks], BF[nf][ks], acc[(MB) + mf][(NB) + nf], \
                            0, 0, 0);                                          \
        __builtin_amdgcn_s_setprio(0);                                         \
    } while (0)

    // ---- prologue: stage buf0 (kt 0) fully + buf1.B (kt 1); read ph1's regs
    stage_half(0, 1, 0, 0);
    stage_half(0, 1, 1, 0);
    stage_half(0, 0, 0, 0);
    stage_half(0, 0, 1, 0);
    stage_half(1, 1, 0, 1);
    stage_half(1, 1, 1, 1);
    asm volatile("s_waitcnt vmcnt(4)" ::: "memory");  // retire all buf0 loads
    BAR();
#pragma unroll
    for (int ks = 0; ks < 2; ++ks) {
#pragma unroll
        for (int mf = 0; mf < 4; ++mf) afA[mf][ks] = read_A(0, mf, ks);
#pragma unroll
        for (int nf = 0; nf < 2; ++nf) bfr01[nf][ks] = read_B(0, nf, ks);
    }

    for (int it = 0; it < NIT; ++it) {
        const int kA = 2 * it + 1;
        const int kB0 = (2 * it + 2) & (NKT - 1);
        const int kB1 = (2 * it + 3) & (NKT - 1);

        // ---- ph1: MFMA(afA,bfr01 | buf0); reads for ph2 (bfr23<-buf0)
        stage_half(1, 0, 0, kA);
#pragma unroll
        for (int ks = 0; ks < 2; ++ks)
#pragma unroll
            for (int nf = 0; nf < 2; ++nf) bfr23[nf][ks] = read_B(0, nf + 2, ks);
        BAR();
        QMFMA(afA, bfr01, 0, 0);
        BAR();
        // ---- ph2: MFMA(afA,bfr23); reads for ph3 (afB<-buf0 m4-7)
        stage_half(1, 0, 1, kA);
#pragma unroll
        for (int ks = 0; ks < 2; ++ks)
#pragma unroll
            for (int mf = 0; mf < 4; ++mf) afB[mf][ks] = read_A(0, mf + 4, ks);
        BAR();
        QMFMA(afA, bfr23, 0, 2);
        BAR();
        // ---- ph3: MFMA(afB,bfr01); no reads; vmcnt(2) retires buf1.B+buf1.A
        stage_half(0, 1, 0, kB0);
        BAR();
        QMFMA(afB, bfr01, 4, 0);
        asm volatile("s_waitcnt vmcnt(2)" ::: "memory");
        BAR();
        // ---- ph4: MFMA(afB,bfr23); reads for ph5 (afA,bfr01 <- buf1)
        stage_half(0, 1, 1, kB0);
#pragma unroll
        for (int ks = 0; ks < 2; ++ks) {
#pragma unroll
            for (int mf = 0; mf < 4; ++mf) afA[mf][ks] = read_A(1, mf, ks);
#pragma unroll
            for (int nf = 0; nf < 2; ++nf) bfr01[nf][ks] = read_B(1, nf, ks);
        }
        BAR();
        QMFMA(afB, bfr23, 4, 2);
        BAR();
        // ---- ph5: MFMA(afA,bfr01 | buf1); reads for ph6 (bfr23<-buf1)
        stage_half(0, 0, 0, kB0);
#pragma unroll
        for (int ks = 0; ks < 2; ++ks)
#pragma unroll
            for (int nf = 0; nf < 2; ++nf) bfr23[nf][ks] = read_B(1, nf + 2, ks);
        BAR();
        QMFMA(afA, bfr01, 0, 0);
        BAR();
        // ---- ph6: MFMA(afA,bfr23); reads for ph7 (afB<-buf1 m4-7)
        stage_half(0, 0, 1, kB0);
#pragma unroll
        for (int ks = 0; ks < 2; ++ks)
#pragma unroll
            for (int mf = 0; mf < 4; ++mf) afB[mf][ks] = read_A(1, mf + 4, ks);
        BAR();
        QMFMA(afA, bfr23, 0, 2);
        BAR();
        // ---- ph7: MFMA(afB,bfr01); no reads; vmcnt(2) retires buf0(kB0)
        stage_half(1, 1, 0, kB1);
        BAR();
        QMFMA(afB, bfr01, 4, 0);
        asm volatile("s_waitcnt vmcnt(2)" ::: "memory");
        BAR();
        // ---- ph8: MFMA(afB,bfr23); reads for next ph1 (afA,bfr01 <- buf0 kB0)
        stage_half(1, 1, 1, kB1);
#pragma unroll
        for (int ks = 0; ks < 2; ++ks) {
#pragma unroll
            for (int mf = 0; mf < 4; ++mf) afA[mf][ks] = read_A(0, mf, ks);
#pragma unroll
            for (int nf = 0; nf < 2; ++nf) bfr01[nf][ks] = read_B(0, nf, ks);
        }
        BAR();
        QMFMA(afB, bfr23, 4, 2);
        BAR();
    }
#undef QMFMA

    // epilogue: C/D layout col = lane&15, row = (lane>>4)*4 + reg
    const int crow0 = brow + wm * 128;
    const int ccol0 = bcol + wn * 64;
#pragma unroll
    for (int mf = 0; mf < 8; ++mf)
#pragma unroll
        for (int nf = 0; nf < 4; ++nf)
#pragma unroll
            for (int r = 0; r < 4; ++r) {
                int row = crow0 + mf * 16 + kgrp * 4 + r;
                int col = ccol0 + nf * 16 + l15;
                C[(size_t)row * N + col] = acc[mf][nf][r];
            }
}

// --- fallback: naive fp32 (never expected to trigger) -----------------------
__global__ void naive_kernel(const float* __restrict__ A, const float* __restrict__ W,
                             float* __restrict__ C, int M, int N, int K) {
    int col = blockIdx.x * blockDim.x + threadIdx.x;
    int row = blockIdx.y;
    if (col >= N || row >= M) return;
    float s = 0.0f;
    for (int k = 0; k < K; ++k) {
        float w = W[(size_t)k * N + col];
        float a = fabsf(w);
        if (a >= 0.5f && a < 1.5f) s += (w > 0.0f) ? A[(size_t)row * K + k] : -A[(size_t)row * K + k];
    }
    C[(size_t)row * N + col] = s;
}

extern "C" void kernel_launch(void* const* d_in, const int* in_sizes, int n_in,
                              void* d_out, int out_size, void* d_ws, size_t ws_size,
                              hipStream_t stream) {
    const float* A = (const float*)d_in[0];  // [M,K]
    const float* W = (const float*)d_in[1];  // [K,N]
    float* C = (float*)d_out;

    constexpr int K = 4096, N = 4096;
    const int M = in_sizes[0] / K;  // 8192

    const size_t needA = (size_t)M * K * 2;
    const size_t needW = (size_t)N * K * 2;
    const bool divisible = (M % BM == 0);
    if (ws_size < needA + needW || !divisible) {
        dim3 grid((N + 255) / 256, M);
        naive_kernel<<<grid, 256, 0, stream>>>(A, W, C, M, N, K);
        return;
    }

    unsigned short* Abf = (unsigned short*)d_ws;
    unsigned short* Wt = (unsigned short*)((char*)d_ws + needA);

    cvtA_kernel<<<2048, 256, 0, stream>>>(A, Abf, (long)M * K / 8);
    ternT_kernel<<<dim3(N / 64, K / 64), 256, 0, stream>>>(W, Wt, K, N);

    const int nwg = (M / BM) * (N / BN);  // 512
    gemm8pp_kernel<N, K><<<dim3(nwg), 512, 0, stream>>>(Abf, Wt, C, M);
}

// Round 6
// 247.602 us; speedup vs baseline: 2.0685x; 2.0685x over previous
//
#include <hip/hip_runtime.h>
#include <hip/hip_bf16.h>

// ---------------------------------------------------------------------------
// TernaryDense: C[M,N] = A[M,K] (fp32) @ ternary(W[K,N]) (fp32)
// Round 6: r4 base, but SINGLE barrier per phase (m201 template structure):
//   {ds_reads_p, stage_p, [vmcnt at ph4/ph8], BAR, setprio, MFMA_p}
// This decouples waves so one wave's ds_reads overlap another's MFMA.
// T1 XCD swizzle, T2 src-side XOR swizzle (0 conflicts), T4 counted vmcnt,
// T5 setprio. Reads feed the SAME phase's MFMA (r5's read-ahead regressed).
// ---------------------------------------------------------------------------

#define LDSP(p) ((__attribute__((address_space(3))) void*)(p))
#define GLBP(p) ((const __attribute__((address_space(1))) void*)(p))

typedef __attribute__((ext_vector_type(8))) short bf16x8;
typedef __attribute__((ext_vector_type(4))) float f32x4;

static __device__ __forceinline__ unsigned short f2bf_rne(float f) {
    unsigned u = __float_as_uint(f);
    unsigned r = (u + 0x7FFFu + ((u >> 16) & 1u)) >> 16;
    return (unsigned short)r;
}

static __device__ __forceinline__ unsigned short tern_bf16(float v) {
    float a = fabsf(v);
    if (a >= 0.5f && a < 1.5f)
        return (v > 0.0f) ? (unsigned short)0x3F80u : (unsigned short)0xBF80u;
    return (unsigned short)0;
}

// --- pre-pass 1: A fp32 -> bf16 ---------------------------------------------
__global__ __launch_bounds__(256) void cvtA_kernel(
    const float* __restrict__ in, unsigned short* __restrict__ out, long n8) {
    long i = (long)blockIdx.x * blockDim.x + threadIdx.x;
    long stride = (long)gridDim.x * blockDim.x;
    for (; i < n8; i += stride) {
        float4 v0 = *(const float4*)(in + i * 8);
        float4 v1 = *(const float4*)(in + i * 8 + 4);
        unsigned short o[8] = {f2bf_rne(v0.x), f2bf_rne(v0.y), f2bf_rne(v0.z), f2bf_rne(v0.w),
                               f2bf_rne(v1.x), f2bf_rne(v1.y), f2bf_rne(v1.z), f2bf_rne(v1.w)};
        *(int4*)(out + i * 8) = *(const int4*)o;
    }
}

// --- pre-pass 2: ternarize W[K,N] and transpose -> Wt[N,K] bf16 -------------
__global__ __launch_bounds__(256) void ternT_kernel(
    const float* __restrict__ W, unsigned short* __restrict__ Wt, int K, int N) {
    __shared__ unsigned short tile[64][72];
    const int k0 = blockIdx.y * 64;
    const int n0 = blockIdx.x * 64;
    const int t = threadIdx.x;
#pragma unroll
    for (int i = 0; i < 4; ++i) {
        int e = i * 1024 + t * 4;
        int r = e >> 6, c = e & 63;
        float4 v = *(const float4*)(W + (size_t)(k0 + r) * N + n0 + c);
        tile[r][c + 0] = tern_bf16(v.x);
        tile[r][c + 1] = tern_bf16(v.y);
        tile[r][c + 2] = tern_bf16(v.z);
        tile[r][c + 3] = tern_bf16(v.w);
    }
    __syncthreads();
#pragma unroll
    for (int i = 0; i < 2; ++i) {
        int e = i * 2048 + t * 8;
        int n = e >> 6, kk = e & 63;
        unsigned short o[8];
#pragma unroll
        for (int j = 0; j < 8; ++j) o[j] = tile[kk + j][n];
        *(int4*)(Wt + (size_t)(n0 + n) * K + k0 + kk) = *(const int4*)o;
    }
}

// --- single-barrier 8-phase 256^2 GEMM, 16x16x32 MFMA -----------------------
#define BM 256
#define BN 256
#define BK 64

#define FENCE() asm volatile("" ::: "memory")
#define BAR()                          \
    do {                               \
        FENCE();                       \
        __builtin_amdgcn_s_barrier();  \
        FENCE();                       \
    } while (0)

template <int N, int K>
__global__ __launch_bounds__(512, 2) void gemm1b_kernel(
    const unsigned short* __restrict__ A,   // M x K bf16
    const unsigned short* __restrict__ Bt,  // N x K bf16
    float* __restrict__ C, int M) {
    __shared__ alignas(16) unsigned short lds[2][2][BM * BK];  // 128 KB

    const int t = threadIdx.x;
    const int lane = t & 63;
    const int wave = t >> 6;
    const int wm = wave >> 2;   // 0..1  -> 128 rows
    const int wn = wave & 3;    // 0..3  -> 64 cols
    const int l15 = lane & 15;
    const int kgrp = lane >> 4; // 0..3

    // T1: bijective XCD swizzle (nwg % 8 == 0)
    const int nbx = N / BN;
    const int nwg = nbx * (M / BM);
    const int qq = nwg >> 3;
    const int swz = ((int)blockIdx.x & 7) * qq + ((int)blockIdx.x >> 3);
    const int brow = (swz / nbx) * BM;
    const int bcol = (swz % nbx) * BN;

    constexpr int NKT = K / BK;   // 64
    constexpr int NIT = NKT / 2;  // 32

    // stage one 16KB half (mat 0=A,1=B; h 0/1) of K-tile kt into buffer b.
    // LDS dest linear; inverse T2 swizzle applied to the GLOBAL source addr.
    auto stage_half = [&](int b, int mat, int h, int kt) {
        const unsigned short* sb = mat ? Bt : A;
        const int rowbase = mat ? bcol : brow;
#pragma unroll
        for (int iss = 0; iss < 2; ++iss) {
            int Lb = h * 16384 + iss * 8192 + t * 16;  // byte in 32KB tile
            int row = Lb >> 7;                          // tile row 0..255
            int kb = (Lb & 127) ^ ((row & 7) << 4);     // swizzled k-byte
            const char* src = (const char*)sb +
                ((size_t)(rowbase + row) * K + (size_t)kt * BK) * 2 + kb;
            unsigned short* dst =
                &lds[b][mat][0] + (h * 16384 + iss * 8192 + wave * 1024) / 2;
            __builtin_amdgcn_global_load_lds(GLBP(src), LDSP(dst), 16, 0, 0);
        }
    };

    auto read_A = [&](int b, int mf, int ks) -> bf16x8 {
        int row = wm * 128 + mf * 16 + l15;
        int kb = (kgrp * 16 + ks * 64) ^ ((row & 7) << 4);
        return *(const bf16x8*)((const char*)&lds[b][0][0] + row * 128 + kb);
    };
    auto read_B = [&](int b, int nf, int ks) -> bf16x8 {
        int row = wn * 64 + nf * 16 + l15;
        int kb = (kgrp * 16 + ks * 64) ^ ((row & 7) << 4);
        return *(const bf16x8*)((const char*)&lds[b][1][0] + row * 128 + kb);
    };

    f32x4 acc[8][4] = {};
    bf16x8 af[4][2], bfr01[2][2], bfr23[2][2];

    // 16 MFMA = one C-quadrant (4 mf x 2 nf x 2 ks)
#define QMFMA(BF, MB, NB)                                                      \
    do {                                                                       \
        __builtin_amdgcn_s_setprio(1);                                         \
        _Pragma("unroll") for (int ks = 0; ks < 2; ++ks)                       \
            _Pragma("unroll") for (int mf = 0; mf < 4; ++mf)                   \
                _Pragma("unroll") for (int nf = 0; nf < 2; ++nf)               \
                    acc[(MB) + mf][(NB) + nf] =                                \
                        __builtin_amdgcn_mfma_f32_16x16x32_bf16(               \
                            af[mf][ks], BF[nf][ks], acc[(MB) + mf][(NB) + nf], \
                            0, 0, 0);                                          \
        __builtin_amdgcn_s_setprio(0);                                         \
    } while (0)

    // prologue: buf0 fully (kt0), buf1.B halves (kt1); wait buf0 only
    stage_half(0, 1, 0, 0);
    stage_half(0, 1, 1, 0);
    stage_half(0, 0, 0, 0);
    stage_half(0, 0, 1, 0);
    stage_half(1, 1, 0, 1);
    stage_half(1, 1, 1, 1);
    asm volatile("s_waitcnt vmcnt(4)" ::: "memory");
    BAR();

    for (int it = 0; it < NIT; ++it) {
        const int kA = 2 * it + 1;                  // buf1.A fill (this iter)
        const int kB0 = (2 * it + 2) & (NKT - 1);   // buf0 next K-tile
        const int kB1 = (2 * it + 3) & (NKT - 1);   // buf1 next K-tile

        // ---- ph1: reads afA(buf0 m0-3) + bfr01(buf0) = 12; stage buf1.A.h0
#pragma unroll
        for (int ks = 0; ks < 2; ++ks) {
#pragma unroll
            for (int mf = 0; mf < 4; ++mf) af[mf][ks] = read_A(0, mf, ks);
#pragma unroll
            for (int nf = 0; nf < 2; ++nf) bfr01[nf][ks] = read_B(0, nf, ks);
        }
        stage_half(1, 0, 0, kA);
        BAR();
        QMFMA(bfr01, 0, 0);
        // ---- ph2: reads bfr23(buf0) = 4; stage buf1.A.h1
#pragma unroll
        for (int ks = 0; ks < 2; ++ks)
#pragma unroll
            for (int nf = 0; nf < 2; ++nf) bfr23[nf][ks] = read_B(0, nf + 2, ks);
        stage_half(1, 0, 1, kA);
        BAR();
        QMFMA(bfr23, 0, 2);
        // ---- ph3: reads afB(buf0 m4-7) = 8; stage buf0.B.h0(kB0)
#pragma unroll
        for (int ks = 0; ks < 2; ++ks)
#pragma unroll
            for (int mf = 0; mf < 4; ++mf) af[mf][ks] = read_A(0, mf + 4, ks);
        stage_half(0, 1, 0, kB0);
        BAR();
        QMFMA(bfr01, 4, 0);
        // ---- ph4: no reads; stage buf0.B.h1(kB0); vmcnt(4) retires buf1(kA)
        stage_half(0, 1, 1, kB0);
        asm volatile("s_waitcnt vmcnt(4)" ::: "memory");
        BAR();
        QMFMA(bfr23, 4, 2);
        // ---- ph5: reads afA(buf1 m0-3) + bfr01(buf1) = 12; stage buf0.A.h0
#pragma unroll
        for (int ks = 0; ks < 2; ++ks) {
#pragma unroll
            for (int mf = 0; mf < 4; ++mf) af[mf][ks] = read_A(1, mf, ks);
#pragma unroll
            for (int nf = 0; nf < 2; ++nf) bfr01[nf][ks] = read_B(1, nf, ks);
        }
        stage_half(0, 0, 0, kB0);
        BAR();
        QMFMA(bfr01, 0, 0);
        // ---- ph6: reads bfr23(buf1) = 4; stage buf0.A.h1
#pragma unroll
        for (int ks = 0; ks < 2; ++ks)
#pragma unroll
            for (int nf = 0; nf < 2; ++nf) bfr23[nf][ks] = read_B(1, nf + 2, ks);
        stage_half(0, 0, 1, kB0);
        BAR();
        QMFMA(bfr23, 0, 2);
        // ---- ph7: reads afB(buf1 m4-7) = 8; stage buf1.B.h0(kB1)
#pragma unroll
        for (int ks = 0; ks < 2; ++ks)
#pragma unroll
            for (int mf = 0; mf < 4; ++mf) af[mf][ks] = read_A(1, mf + 4, ks);
        stage_half(1, 1, 0, kB1);
        BAR();
        QMFMA(bfr01, 4, 0);
        // ---- ph8: no reads; stage buf1.B.h1(kB1); vmcnt(4) retires buf0(kB0)
        stage_half(1, 1, 1, kB1);
        asm volatile("s_waitcnt vmcnt(4)" ::: "memory");
        BAR();
        QMFMA(bfr23, 4, 2);
    }
#undef QMFMA

    // epilogue: C/D layout col = lane&15, row = (lane>>4)*4 + reg
    const int crow0 = brow + wm * 128;
    const int ccol0 = bcol + wn * 64;
#pragma unroll
    for (int mf = 0; mf < 8; ++mf)
#pragma unroll
        for (int nf = 0; nf < 4; ++nf)
#pragma unroll
            for (int r = 0; r < 4; ++r) {
                int row = crow0 + mf * 16 + kgrp * 4 + r;
                int col = ccol0 + nf * 16 + l15;
                C[(size_t)row * N + col] = acc[mf][nf][r];
            }
}

// --- fallback: naive fp32 (never expected to trigger) -----------------------
__global__ void naive_kernel(const float* __restrict__ A, const float* __restrict__ W,
                             float* __restrict__ C, int M, int N, int K) {
    int col = blockIdx.x * blockDim.x + threadIdx.x;
    int row = blockIdx.y;
    if (col >= N || row >= M) return;
    float s = 0.0f;
    for (int k = 0; k < K; ++k) {
        float w = W[(size_t)k * N + col];
        float a = fabsf(w);
        if (a >= 0.5f && a < 1.5f) s += (w > 0.0f) ? A[(size_t)row * K + k] : -A[(size_t)row * K + k];
    }
    C[(size_t)row * N + col] = s;
}

extern "C" void kernel_launch(void* const* d_in, const int* in_sizes, int n_in,
                              void* d_out, int out_size, void* d_ws, size_t ws_size,
                              hipStream_t stream) {
    const float* A = (const float*)d_in[0];  // [M,K]
    const float* W = (const float*)d_in[1];  // [K,N]
    float* C = (float*)d_out;

    constexpr int K = 4096, N = 4096;
    const int M = in_sizes[0] / K;  // 8192

    const size_t needA = (size_t)M * K * 2;
    const size_t needW = (size_t)N * K * 2;
    const bool divisible = (M % BM == 0);
    if (ws_size < needA + needW || !divisible) {
        dim3 grid((N + 255) / 256, M);
        naive_kernel<<<grid, 256, 0, stream>>>(A, W, C, M, N, K);
        return;
    }

    unsigned short* Abf = (unsigned short*)d_ws;
    unsigned short* Wt = (unsigned short*)((char*)d_ws + needA);

    cvtA_kernel<<<2048, 256, 0, stream>>>(A, Abf, (long)M * K / 8);
    ternT_kernel<<<dim3(N / 64, K / 64), 256, 0, stream>>>(W, Wt, K, N);

    const int nwg = (M / BM) * (N / BN);  // 512
    gemm1b_kernel<N, K><<<dim3(nwg), 512, 0, stream>>>(Abf, Wt, C, M);
}